// Round 20
// baseline (152.382 us; speedup 1.0000x reference)
//
#include <hip/hip_runtime.h>

#define N_NODES 150000
#define N_EDGES 2400000
#define F_IN    22
#define HID     32
#define N_CLS   6
#define BN_EPS  1e-5f

#define BSHIFT  9
#define BMASK   511
#define NB      ((N_NODES + BMASK) >> BSHIFT)       // 293 buckets of 512 nodes
#define NBLK_BIN 512                                // 2 bin blocks per CU (TLP)
#define CHUNK   ((N_EDGES + NBLK_BIN - 1) / NBLK_BIN)   // 4688 edges per block
                                                    // runs ~= CHUNK/NB ~ 16 = 64 B (safe)
#define CHUNK_H 8192
#define NBLK_H  ((N_EDGES + CHUNK_H - 1) / CHUNK_H) // 293 hist blocks
#define EMB_NPB 64                                  // nodes per embed block
#define NBLK_EMB ((N_NODES + EMB_NPB - 1) / EMB_NPB)    // 2344 embed blocks
#define NREP    8                                   // stats replicas

// bf16 round-to-nearest-even, packed storage helpers
__device__ __forceinline__ unsigned bf16rne(float f) {
    unsigned u = __float_as_uint(f);
    return (u + 0x7FFFu + ((u >> 16) & 1u)) >> 16;
}
__device__ __forceinline__ float bflo(unsigned p) { return __uint_as_float(p << 16); }
__device__ __forceinline__ float bfhi(unsigned p) { return __uint_as_float(p & 0xFFFF0000u); }

// ---------------------------------------------------------------------------
// K0 (fused): blocks [0,NBLK_EMB): embed 64 nodes, 4 threads/node, q=tid&3,
//   b128 weight reads (r18-proven). sx pad 25 (coprime 32; 24 gave 4-way).
//   blocks [NBLK_EMB, +NBLK_H): bucket histogram of dst.
// ---------------------------------------------------------------------------
__global__ void embed_hist_kernel(const float* __restrict__ x,
                                  const float* __restrict__ W_emb,
                                  const float* __restrict__ b_emb,
                                  const float* __restrict__ W_gcn,
                                  unsigned* __restrict__ hb,
                                  const int* __restrict__ dst,
                                  int* __restrict__ bcnt) {
    if (blockIdx.x < NBLK_EMB) {
        __shared__ float sWe[F_IN * HID];
        __shared__ float sbe[HID];
        __shared__ float sWg[HID * HID];
        __shared__ float sx[EMB_NPB * 25];
        __shared__ float sh1[EMB_NPB * 33];
        for (int t = threadIdx.x; t < F_IN * HID; t += 256) sWe[t] = W_emb[t];
        if (threadIdx.x < HID) sbe[threadIdx.x] = b_emb[threadIdx.x];
        for (int t = threadIdx.x; t < HID * HID; t += 256) sWg[t] = W_gcn[t];

        int nbase = blockIdx.x * EMB_NPB;
        int nvalid = N_NODES - nbase; if (nvalid > EMB_NPB) nvalid = EMB_NPB;

        {   // coalesced stage of this block's x rows
            const float* xg = x + (size_t)nbase * F_IN;
            int totalx = nvalid * F_IN;
            for (int L = threadIdx.x; L < totalx; L += 256)
                sx[(L / F_IN) * 25 + (L % F_IN)] = xg[L];
        }
        __syncthreads();

        int n = threadIdx.x >> 2;
        int q = threadIdx.x & 3;
        bool act = n < nvalid;

        if (act) {                     // phase 2: h1 slice, b128 weights
            float xr[F_IN];
#pragma unroll
            for (int f = 0; f < F_IN; ++f) xr[f] = sx[n * 25 + f];
            float acc[8];
#pragma unroll
            for (int j = 0; j < 8; ++j) acc[j] = sbe[q * 8 + j];
#pragma unroll
            for (int f = 0; f < F_IN; ++f) {
                float4 wa = *reinterpret_cast<const float4*>(&sWe[f * HID + q * 8]);
                float4 wb = *reinterpret_cast<const float4*>(&sWe[f * HID + q * 8 + 4]);
                acc[0] = fmaf(xr[f], wa.x, acc[0]);
                acc[1] = fmaf(xr[f], wa.y, acc[1]);
                acc[2] = fmaf(xr[f], wa.z, acc[2]);
                acc[3] = fmaf(xr[f], wa.w, acc[3]);
                acc[4] = fmaf(xr[f], wb.x, acc[4]);
                acc[5] = fmaf(xr[f], wb.y, acc[5]);
                acc[6] = fmaf(xr[f], wb.z, acc[6]);
                acc[7] = fmaf(xr[f], wb.w, acc[7]);
            }
#pragma unroll
            for (int j = 0; j < 8; ++j)
                sh1[n * 33 + q * 8 + j] = fmaxf(acc[j], 0.0f);
        }
        __syncthreads();

        if (act) {                     // phase 3: output slice, b128 weights
            float hr[HID];
#pragma unroll
            for (int f = 0; f < HID; ++f) hr[f] = sh1[n * 33 + f];
            float o[8];
#pragma unroll
            for (int j = 0; j < 8; ++j) o[j] = 0.0f;
#pragma unroll
            for (int f = 0; f < HID; ++f) {
                float4 wa = *reinterpret_cast<const float4*>(&sWg[f * HID + q * 8]);
                float4 wb = *reinterpret_cast<const float4*>(&sWg[f * HID + q * 8 + 4]);
                o[0] = fmaf(hr[f], wa.x, o[0]);
                o[1] = fmaf(hr[f], wa.y, o[1]);
                o[2] = fmaf(hr[f], wa.z, o[2]);
                o[3] = fmaf(hr[f], wa.w, o[3]);
                o[4] = fmaf(hr[f], wb.x, o[4]);
                o[5] = fmaf(hr[f], wb.y, o[5]);
                o[6] = fmaf(hr[f], wb.z, o[6]);
                o[7] = fmaf(hr[f], wb.w, o[7]);
            }
            uint4 u;
            u.x = bf16rne(o[0]) | (bf16rne(o[1]) << 16);
            u.y = bf16rne(o[2]) | (bf16rne(o[3]) << 16);
            u.z = bf16rne(o[4]) | (bf16rne(o[5]) << 16);
            u.w = bf16rne(o[6]) | (bf16rne(o[7]) << 16);
            reinterpret_cast<uint4*>(hb)[(size_t)(nbase + n) * 4 + q] = u;
        }
    } else {
        __shared__ int hloc[NB];
        for (int t = threadIdx.x; t < NB; t += 256) hloc[t] = 0;
        __syncthreads();
        int base = (blockIdx.x - NBLK_EMB) * CHUNK_H;
        int end = base + CHUNK_H; if (end > N_EDGES) end = N_EDGES;
        for (int i = base + threadIdx.x; i < end; i += 256)
            atomicAdd(&hloc[dst[i] >> BSHIFT], 1);
        __syncthreads();
        for (int t = threadIdx.x; t < NB; t += 256)
            if (hloc[t]) atomicAdd(&bcnt[t], hloc[t]);
    }
}

// ---------------------------------------------------------------------------
// K1: single-block exclusive scan of NB bucket counts -> boff, bcur;
//     also zeros the stats replicas
// ---------------------------------------------------------------------------
__global__ void bucket_scan_kernel(const int* __restrict__ bcnt,
                                   int* __restrict__ boff,
                                   int* __restrict__ bcur,
                                   float* __restrict__ stats) {
    int t = threadIdx.x;
    if (t < 64 * NREP) stats[t] = 0.0f;
    __shared__ int s[1024];
    int v0 = (t < NB) ? bcnt[t] : 0;
    s[t] = v0;
    __syncthreads();
#pragma unroll
    for (int o = 1; o < 1024; o <<= 1) {
        int v = (t >= o) ? s[t - o] : 0;
        __syncthreads();
        s[t] += v;
        __syncthreads();
    }
    if (t < NB) {
        int e = s[t] - v0;
        boff[t] = e;
        bcur[t] = e;
    }
    if (t == NB - 1) boff[NB] = s[t];
}

// ---------------------------------------------------------------------------
// K2: binned append, 512 blocks x 512 threads (2 blocks/CU = 4 waves/SIMD;
//     BSHIFT=9 keeps write runs at ~16 entries = 64 B despite halved CHUNK).
//     Runs ALONE (write-combining needs L2 to itself).
//     packed = (dst & 511) << 23 | src   (src < 2^18)
// ---------------------------------------------------------------------------
__global__ void bin_edges_kernel(const int* __restrict__ src,
                                 const int* __restrict__ dst,
                                 int* __restrict__ bcur,
                                 unsigned int* __restrict__ binned) {
    __shared__ int hloc[NB];
    __shared__ int base[NB];
    __shared__ int lcur[NB];
    for (int t = threadIdx.x; t < NB; t += 512) hloc[t] = 0;
    __syncthreads();

    int cbase = blockIdx.x * CHUNK;
    int cend = cbase + CHUNK; if (cend > N_EDGES) cend = N_EDGES;
    for (int i = cbase + threadIdx.x; i < cend; i += 512)
        atomicAdd(&hloc[dst[i] >> BSHIFT], 1);
    __syncthreads();
    for (int t = threadIdx.x; t < NB; t += 512) {
        int c = hloc[t];
        base[t] = c ? atomicAdd(&bcur[t], c) : 0;
        lcur[t] = 0;
    }
    __syncthreads();
    for (int i = cbase + threadIdx.x; i < cend; i += 512) {
        int d = dst[i];
        int b = d >> BSHIFT;
        int r = atomicAdd(&lcur[b], 1);
        binned[base[b] + r] = ((unsigned)(d & BMASK) << 23) | (unsigned)src[i];
    }
}

// ---------------------------------------------------------------------------
// K3: per-bucket counting sort (512-node buckets, 512 threads) -> dst-sorted
//     sorted_src + off[] + dis, AND in-place bf16 pre-scale of the bucket's
//     hb rows: hs = h * dis.  Writes stay in this bucket's 32 KB window.
// ---------------------------------------------------------------------------
__global__ void bucket_csr_kernel(const int* __restrict__ boff,
                                  const unsigned int* __restrict__ binned,
                                  int* __restrict__ sorted_src,
                                  int* __restrict__ off,
                                  float* __restrict__ dis,
                                  unsigned* __restrict__ hb) {
    __shared__ int s_cnt[512];
    __shared__ int s_scan[512];
    __shared__ int s_cur[512];
    __shared__ float dl[512];
    int b = blockIdx.x;
    int t = threadIdx.x;
    int s0 = boff[b], s1 = boff[b + 1];
    int nbase = b << BSHIFT;
    int nnode = N_NODES - nbase; if (nnode > 512) nnode = 512;

    s_cnt[t] = 0;
    __syncthreads();
    for (int k = s0 + t; k < s1; k += 512)
        atomicAdd(&s_cnt[binned[k] >> 23], 1);
    __syncthreads();

    int v = s_cnt[t];
    s_scan[t] = v;
    __syncthreads();
#pragma unroll
    for (int o = 1; o < 512; o <<= 1) {
        int u = (t >= o) ? s_scan[t - o] : 0;
        __syncthreads();
        s_scan[t] += u;
        __syncthreads();
    }
    int excl = s_scan[t] - v;
    s_cur[t] = excl;
    float d = rsqrtf(1.0f + (float)v);
    dl[t] = d;
    if (t < nnode) {
        off[nbase + t] = s0 + excl;
        dis[nbase + t] = d;
    }
    if (b == NB - 1 && t == 0) off[N_NODES] = N_EDGES;
    __syncthreads();

    for (int k = s0 + t; k < s1; k += 512) {
        unsigned p = binned[k];
        int n = (int)(p >> 23);
        int r = atomicAdd(&s_cur[n], 1);
        sorted_src[s0 + r] = (int)(p & 0x7FFFFFu);
    }

    // in-place bf16 pre-scale of this bucket's hb rows (coalesced 32 KB)
    uint2* hv = reinterpret_cast<uint2*>(hb) + (size_t)nbase * 8;
    for (int tt = t; tt < nnode * 8; tt += 512) {
        uint2 w = hv[tt];
        float dd = dl[tt >> 3];
        w.x = bf16rne(bflo(w.x) * dd) | (bf16rne(bfhi(w.x) * dd) << 16);
        w.y = bf16rne(bflo(w.y) * dd) | (bf16rne(bfhi(w.y) * dd) << 16);
        hv[tt] = w;
    }
}

// ---------------------------------------------------------------------------
// K4: per-node aggregation + fused BN-stats.  4 threads/node, uint4 (16 B)
//     gathers; 4-wide edge ILP with idx double-buffer; 2 accumulator banks.
//     agg[n] = (hs[n] + sum_{in(n)} hs[s]) * dis[n]
// ---------------------------------------------------------------------------
__global__ void aggregate_kernel(const int* __restrict__ off,
                                 const int* __restrict__ sorted_src,
                                 const unsigned* __restrict__ hb,
                                 const float* __restrict__ dis,
                                 float* __restrict__ agg,
                                 float* __restrict__ stats) {
    int t = blockIdx.x * blockDim.x + threadIdx.x;
    int node = t >> 2;
    int c = t & 3;                 // 8-feature slice (16 B of the 64 B row)
    bool active = node < N_NODES;

    float o[8];
#pragma unroll
    for (int j = 0; j < 8; ++j) o[j] = 0.0f;

    if (active) {
        const uint4* hrow = reinterpret_cast<const uint4*>(hb);
        float dn = dis[node];
        uint4 hp = hrow[(size_t)node * 4 + c];
        float a0[8], a1[8];
        a0[0] = bflo(hp.x); a0[1] = bfhi(hp.x);
        a0[2] = bflo(hp.y); a0[3] = bfhi(hp.y);
        a0[4] = bflo(hp.z); a0[5] = bfhi(hp.z);
        a0[6] = bflo(hp.w); a0[7] = bfhi(hp.w);
#pragma unroll
        for (int j = 0; j < 8; ++j) a1[j] = 0.0f;

        int b0 = off[node], e0 = off[node + 1];
        int cnt4 = (e0 - b0) >> 2;
        int k = b0;
        int p0 = 0, p1 = 0, p2 = 0, p3 = 0;
        if (cnt4 > 0) {
            p0 = sorted_src[k];     p1 = sorted_src[k + 1];
            p2 = sorted_src[k + 2]; p3 = sorted_src[k + 3];
        }
        for (int it = 0; it < cnt4; ++it) {
            int kn = k + 4;
            int n0 = p0, n1 = p1, n2 = p2, n3 = p3;
            if (it + 1 < cnt4) {                    // prefetch next chunk idx
                n0 = sorted_src[kn];     n1 = sorted_src[kn + 1];
                n2 = sorted_src[kn + 2]; n3 = sorted_src[kn + 3];
            }
            uint4 v0 = hrow[(size_t)p0 * 4 + c];
            uint4 v1 = hrow[(size_t)p1 * 4 + c];
            uint4 v2 = hrow[(size_t)p2 * 4 + c];
            uint4 v3 = hrow[(size_t)p3 * 4 + c];
            a0[0] += bflo(v0.x); a0[1] += bfhi(v0.x);
            a0[2] += bflo(v0.y); a0[3] += bfhi(v0.y);
            a0[4] += bflo(v0.z); a0[5] += bfhi(v0.z);
            a0[6] += bflo(v0.w); a0[7] += bfhi(v0.w);
            a1[0] += bflo(v1.x); a1[1] += bfhi(v1.x);
            a1[2] += bflo(v1.y); a1[3] += bfhi(v1.y);
            a1[4] += bflo(v1.z); a1[5] += bfhi(v1.z);
            a1[6] += bflo(v1.w); a1[7] += bfhi(v1.w);
            a0[0] += bflo(v2.x); a0[1] += bfhi(v2.x);
            a0[2] += bflo(v2.y); a0[3] += bfhi(v2.y);
            a0[4] += bflo(v2.z); a0[5] += bfhi(v2.z);
            a0[6] += bflo(v2.w); a0[7] += bfhi(v2.w);
            a1[0] += bflo(v3.x); a1[1] += bfhi(v3.x);
            a1[2] += bflo(v3.y); a1[3] += bfhi(v3.y);
            a1[4] += bflo(v3.z); a1[5] += bfhi(v3.z);
            a1[6] += bflo(v3.w); a1[7] += bfhi(v3.w);
            p0 = n0; p1 = n1; p2 = n2; p3 = n3;
            k = kn;
        }
        for (; k < e0; ++k) {
            int s = sorted_src[k];
            uint4 v = hrow[(size_t)s * 4 + c];
            a0[0] += bflo(v.x); a0[1] += bfhi(v.x);
            a0[2] += bflo(v.y); a0[3] += bfhi(v.y);
            a0[4] += bflo(v.z); a0[5] += bfhi(v.z);
            a0[6] += bflo(v.w); a0[7] += bfhi(v.w);
        }
#pragma unroll
        for (int j = 0; j < 8; ++j) o[j] = (a0[j] + a1[j]) * dn;
        float4 w0 = {o[0], o[1], o[2], o[3]};
        float4 w1 = {o[4], o[5], o[6], o[7]};
        float4* ag = reinterpret_cast<float4*>(agg) + (size_t)node * 8 + c * 2;
        ag[0] = w0;
        ag[1] = w1;
    }

    // block-level stats reduce (all 256 threads reach barriers)
    __shared__ float S[256 * 9];   // pad 9: write/read bank-safe
    __shared__ float Q[256 * 9];
#pragma unroll
    for (int j = 0; j < 8; ++j) {
        S[threadIdx.x * 9 + j] = o[j];
        Q[threadIdx.x * 9 + j] = o[j] * o[j];
    }
    __syncthreads();
    if (threadIdx.x < 32) {
        int cc = threadIdx.x >> 3, j = threadIdx.x & 7;   // feature f = cc*8+j = tid
        float s = 0.0f, q = 0.0f;
#pragma unroll
        for (int w = 0; w < 64; ++w) {                    // threads with tid&3==cc
            int tid = (w << 2) | cc;
            s += S[tid * 9 + j];
            q += Q[tid * 9 + j];
        }
        float* rep = stats + 64 * (blockIdx.x & (NREP - 1));
        atomicAdd(&rep[threadIdx.x], s);
        atomicAdd(&rep[32 + threadIdx.x], q);
    }
}

// ---------------------------------------------------------------------------
// K5: out = relu(agg*A + B) @ W_cls + b_cls   (BN fold from NREP stat replicas)
// ---------------------------------------------------------------------------
__global__ void cls_kernel(const float* __restrict__ agg,
                           const float* __restrict__ stats,
                           const float* __restrict__ gamma,
                           const float* __restrict__ beta,
                           const float* __restrict__ W_cls,
                           const float* __restrict__ b_cls,
                           float* __restrict__ out) {
    __shared__ float sA[HID];
    __shared__ float sB[HID];
    __shared__ float sW[HID * N_CLS];
    __shared__ float sb[N_CLS];
    if (threadIdx.x < HID) {
        float sum = 0.0f, sq = 0.0f;
#pragma unroll
        for (int r = 0; r < NREP; ++r) {
            sum += stats[r * 64 + threadIdx.x];
            sq  += stats[r * 64 + 32 + threadIdx.x];
        }
        const float invN = 1.0f / (float)N_NODES;
        float mean = sum * invN;
        float var = sq * invN - mean * mean;
        float inv = rsqrtf(var + BN_EPS);
        float A = gamma[threadIdx.x] * inv;
        sA[threadIdx.x] = A;
        sB[threadIdx.x] = beta[threadIdx.x] - mean * A;
    }
    for (int t = threadIdx.x; t < HID * N_CLS; t += blockDim.x) sW[t] = W_cls[t];
    if (threadIdx.x < N_CLS) sb[threadIdx.x] = b_cls[threadIdx.x];
    __syncthreads();

    int i = blockIdx.x * blockDim.x + threadIdx.x;
    if (i >= N_NODES) return;

    float acc[N_CLS];
#pragma unroll
    for (int c = 0; c < N_CLS; ++c) acc[c] = sb[c];
#pragma unroll
    for (int f = 0; f < HID; ++f) {
        float t = fmaxf(fmaf(agg[(size_t)i * HID + f], sA[f], sB[f]), 0.0f);
#pragma unroll
        for (int c = 0; c < N_CLS; ++c) acc[c] = fmaf(t, sW[f * N_CLS + c], acc[c]);
    }
#pragma unroll
    for (int c = 0; c < N_CLS; ++c) out[(size_t)i * N_CLS + c] = acc[c];
}

// ---------------------------------------------------------------------------
extern "C" void kernel_launch(void* const* d_in, const int* in_sizes, int n_in,
                              void* d_out, int out_size, void* d_ws, size_t ws_size,
                              hipStream_t stream) {
    const float* x     = (const float*)d_in[0];
    const int*   edge  = (const int*)d_in[1];   // [2, E] int32
    const float* W_emb = (const float*)d_in[2];
    const float* b_emb = (const float*)d_in[3];
    const float* W_gcn = (const float*)d_in[4];
    // d_in[5] = b_gcn: cancels exactly in BatchNorm -> skip
    const float* gamma = (const float*)d_in[6];
    const float* beta  = (const float*)d_in[7];
    const float* W_cls = (const float*)d_in[8];
    const float* b_cls = (const float*)d_in[9];
    float* out = (float*)d_out;

    // workspace layout (~49 MB)
    unsigned*     hb         = (unsigned*)d_ws;                 // N*HID/2 uints (bf16 x2)
    float*        agg        = (float*)(hb + (size_t)N_NODES * HID / 2);  // N*HID
    float*        dis        = agg + (size_t)N_NODES * HID;     // N
    int*          off        = (int*)(dis + N_NODES);           // N+1
    int*          bcnt       = off + N_NODES + 1;               // NB
    int*          boff       = bcnt + NB;                       // NB+1
    int*          bcur       = boff + NB + 1;                   // NB
    unsigned int* binned     = (unsigned int*)(bcur + NB);      // E
    int*          sorted_src = (int*)(binned + N_EDGES);        // E
    float*        stats      = (float*)(sorted_src + N_EDGES);  // 64*NREP

    hipMemsetAsync(bcnt, 0, NB * sizeof(int), stream);

    const int* src = edge;
    const int* dst = edge + N_EDGES;

    embed_hist_kernel<<<NBLK_EMB + NBLK_H, 256, 0, stream>>>(x, W_emb, b_emb, W_gcn,
                                                             hb, dst, bcnt);
    bucket_scan_kernel<<<1, 1024, 0, stream>>>(bcnt, boff, bcur, stats);
    bin_edges_kernel<<<NBLK_BIN, 512, 0, stream>>>(src, dst, bcur, binned);
    bucket_csr_kernel<<<NB, 512, 0, stream>>>(boff, binned, sorted_src, off, dis, hb);
    aggregate_kernel<<<(N_NODES * 4 + 255) / 256, 256, 0, stream>>>(off, sorted_src,
                                                                    hb, dis, agg, stats);
    cls_kernel<<<(N_NODES + 255) / 256, 256, 0, stream>>>(agg, stats, gamma, beta,
                                                          W_cls, b_cls, out);
}

// Round 21
// 143.387 us; speedup vs baseline: 1.0627x; 1.0627x over previous
//
#include <hip/hip_runtime.h>

#define N_NODES 150000
#define N_EDGES 2400000
#define F_IN    22
#define HID     32
#define N_CLS   6
#define BN_EPS  1e-5f

#define BSHIFT  8
#define BMASK   255
#define NB      ((N_NODES + BMASK) >> BSHIFT)       // 586 buckets of 256 nodes
#define NBLK_BIN 256                                // one bin block per CU
#define CHUNK   ((N_EDGES + NBLK_BIN - 1) / NBLK_BIN)   // 9375 edges per block
#define CHUNK_H 8192
#define NBLK_H  ((N_EDGES + CHUNK_H - 1) / CHUNK_H) // 293 hist blocks
#define EMB_NPB 64                                  // nodes per embed block
#define NBLK_EMB ((N_NODES + EMB_NPB - 1) / EMB_NPB)    // 2344 embed blocks
#define NREP    8                                   // stats replicas

// bf16 round-to-nearest-even, packed storage helpers
__device__ __forceinline__ unsigned bf16rne(float f) {
    unsigned u = __float_as_uint(f);
    return (u + 0x7FFFu + ((u >> 16) & 1u)) >> 16;
}
__device__ __forceinline__ float bflo(unsigned p) { return __uint_as_float(p << 16); }
__device__ __forceinline__ float bfhi(unsigned p) { return __uint_as_float(p & 0xFFFF0000u); }

// ---------------------------------------------------------------------------
// K0 (fused): blocks [0,NBLK_EMB): embed 64 nodes, 4 threads/node, q=tid&3,
//   b128 weight reads (r18-proven: each float4 pair replaces 8 scalar reads).
//   blocks [NBLK_EMB, +NBLK_H): bucket histogram of dst (r13-proven).
// ---------------------------------------------------------------------------
__global__ void embed_hist_kernel(const float* __restrict__ x,
                                  const float* __restrict__ W_emb,
                                  const float* __restrict__ b_emb,
                                  const float* __restrict__ W_gcn,
                                  unsigned* __restrict__ hb,
                                  const int* __restrict__ dst,
                                  int* __restrict__ bcnt) {
    if (blockIdx.x < NBLK_EMB) {
        __shared__ float sWe[F_IN * HID];
        __shared__ float sbe[HID];
        __shared__ float sWg[HID * HID];
        __shared__ float sx[EMB_NPB * 24];
        __shared__ float sh1[EMB_NPB * 33];
        for (int t = threadIdx.x; t < F_IN * HID; t += 256) sWe[t] = W_emb[t];
        if (threadIdx.x < HID) sbe[threadIdx.x] = b_emb[threadIdx.x];
        for (int t = threadIdx.x; t < HID * HID; t += 256) sWg[t] = W_gcn[t];

        int nbase = blockIdx.x * EMB_NPB;
        int nvalid = N_NODES - nbase; if (nvalid > EMB_NPB) nvalid = EMB_NPB;

        {   // coalesced stage of this block's x rows
            const float* xg = x + (size_t)nbase * F_IN;
            int totalx = nvalid * F_IN;
            for (int L = threadIdx.x; L < totalx; L += 256)
                sx[(L / F_IN) * 24 + (L % F_IN)] = xg[L];
        }
        __syncthreads();

        int n = threadIdx.x >> 2;
        int q = threadIdx.x & 3;
        bool act = n < nvalid;

        if (act) {                     // phase 2: h1 slice, b128 weights
            float xr[F_IN];
#pragma unroll
            for (int f = 0; f < F_IN; ++f) xr[f] = sx[n * 24 + f];
            float acc[8];
#pragma unroll
            for (int j = 0; j < 8; ++j) acc[j] = sbe[q * 8 + j];
#pragma unroll
            for (int f = 0; f < F_IN; ++f) {
                float4 wa = *reinterpret_cast<const float4*>(&sWe[f * HID + q * 8]);
                float4 wb = *reinterpret_cast<const float4*>(&sWe[f * HID + q * 8 + 4]);
                acc[0] = fmaf(xr[f], wa.x, acc[0]);
                acc[1] = fmaf(xr[f], wa.y, acc[1]);
                acc[2] = fmaf(xr[f], wa.z, acc[2]);
                acc[3] = fmaf(xr[f], wa.w, acc[3]);
                acc[4] = fmaf(xr[f], wb.x, acc[4]);
                acc[5] = fmaf(xr[f], wb.y, acc[5]);
                acc[6] = fmaf(xr[f], wb.z, acc[6]);
                acc[7] = fmaf(xr[f], wb.w, acc[7]);
            }
#pragma unroll
            for (int j = 0; j < 8; ++j)
                sh1[n * 33 + q * 8 + j] = fmaxf(acc[j], 0.0f);
        }
        __syncthreads();

        if (act) {                     // phase 3: output slice, b128 weights
            float hr[HID];
#pragma unroll
            for (int f = 0; f < HID; ++f) hr[f] = sh1[n * 33 + f];
            float o[8];
#pragma unroll
            for (int j = 0; j < 8; ++j) o[j] = 0.0f;
#pragma unroll
            for (int f = 0; f < HID; ++f) {
                float4 wa = *reinterpret_cast<const float4*>(&sWg[f * HID + q * 8]);
                float4 wb = *reinterpret_cast<const float4*>(&sWg[f * HID + q * 8 + 4]);
                o[0] = fmaf(hr[f], wa.x, o[0]);
                o[1] = fmaf(hr[f], wa.y, o[1]);
                o[2] = fmaf(hr[f], wa.z, o[2]);
                o[3] = fmaf(hr[f], wa.w, o[3]);
                o[4] = fmaf(hr[f], wb.x, o[4]);
                o[5] = fmaf(hr[f], wb.y, o[5]);
                o[6] = fmaf(hr[f], wb.z, o[6]);
                o[7] = fmaf(hr[f], wb.w, o[7]);
            }
            uint4 u;
            u.x = bf16rne(o[0]) | (bf16rne(o[1]) << 16);
            u.y = bf16rne(o[2]) | (bf16rne(o[3]) << 16);
            u.z = bf16rne(o[4]) | (bf16rne(o[5]) << 16);
            u.w = bf16rne(o[6]) | (bf16rne(o[7]) << 16);
            reinterpret_cast<uint4*>(hb)[(size_t)(nbase + n) * 4 + q] = u;
        }
    } else {
        __shared__ int hloc[NB];
        for (int t = threadIdx.x; t < NB; t += 256) hloc[t] = 0;
        __syncthreads();
        int base = (blockIdx.x - NBLK_EMB) * CHUNK_H;
        int end = base + CHUNK_H; if (end > N_EDGES) end = N_EDGES;
        for (int i = base + threadIdx.x; i < end; i += 256)
            atomicAdd(&hloc[dst[i] >> BSHIFT], 1);
        __syncthreads();
        for (int t = threadIdx.x; t < NB; t += 256)
            if (hloc[t]) atomicAdd(&bcnt[t], hloc[t]);
    }
}

// ---------------------------------------------------------------------------
// K1: single-block exclusive scan of NB bucket counts -> boff, bcur;
//     also zeros the stats replicas
// ---------------------------------------------------------------------------
__global__ void bucket_scan_kernel(const int* __restrict__ bcnt,
                                   int* __restrict__ boff,
                                   int* __restrict__ bcur,
                                   float* __restrict__ stats) {
    int t = threadIdx.x;
    if (t < 64 * NREP) stats[t] = 0.0f;
    __shared__ int s[1024];
    int v0 = (t < NB) ? bcnt[t] : 0;
    s[t] = v0;
    __syncthreads();
#pragma unroll
    for (int o = 1; o < 1024; o <<= 1) {
        int v = (t >= o) ? s[t - o] : 0;
        __syncthreads();
        s[t] += v;
        __syncthreads();
    }
    if (t < NB) {
        int e = s[t] - v0;
        boff[t] = e;
        bcur[t] = e;
    }
    if (t == NB - 1) boff[NB] = s[t];
}

// ---------------------------------------------------------------------------
// K2: binned append, 256 blocks x 512 threads (r13 proven). Runs ALONE
//     (write-combining needs L2 to itself). A/B r20: occupancy-insensitive
//     (LDS-atomic serialization bound) — keep this geometry.
//     packed = (dst & 255) << 24 | src
// ---------------------------------------------------------------------------
__global__ void bin_edges_kernel(const int* __restrict__ src,
                                 const int* __restrict__ dst,
                                 int* __restrict__ bcur,
                                 unsigned int* __restrict__ binned) {
    __shared__ int hloc[NB];
    __shared__ int base[NB];
    __shared__ int lcur[NB];
    for (int t = threadIdx.x; t < NB; t += 512) hloc[t] = 0;
    __syncthreads();

    int cbase = blockIdx.x * CHUNK;
    int cend = cbase + CHUNK; if (cend > N_EDGES) cend = N_EDGES;
    for (int i = cbase + threadIdx.x; i < cend; i += 512)
        atomicAdd(&hloc[dst[i] >> BSHIFT], 1);
    __syncthreads();
    for (int t = threadIdx.x; t < NB; t += 512) {
        int c = hloc[t];
        base[t] = c ? atomicAdd(&bcur[t], c) : 0;
        lcur[t] = 0;
    }
    __syncthreads();
    for (int i = cbase + threadIdx.x; i < cend; i += 512) {
        int d = dst[i];
        int b = d >> BSHIFT;
        int r = atomicAdd(&lcur[b], 1);
        binned[base[b] + r] = ((unsigned)(d & BMASK) << 24) | (unsigned)src[i];
    }
}

// ---------------------------------------------------------------------------
// K3: per-bucket counting sort -> dst-sorted sorted_src + off[] + dis, AND
//     in-place bf16 pre-scale of the bucket's hb rows: hs = h * dis
// ---------------------------------------------------------------------------
__global__ void bucket_csr_kernel(const int* __restrict__ boff,
                                  const unsigned int* __restrict__ binned,
                                  int* __restrict__ sorted_src,
                                  int* __restrict__ off,
                                  float* __restrict__ dis,
                                  unsigned* __restrict__ hb) {
    __shared__ int s_cnt[256];
    __shared__ int s_scan[256];
    __shared__ int s_cur[256];
    __shared__ float dl[256];
    int b = blockIdx.x;
    int t = threadIdx.x;
    int s0 = boff[b], s1 = boff[b + 1];
    int nbase = b << BSHIFT;
    int nnode = N_NODES - nbase; if (nnode > 256) nnode = 256;

    s_cnt[t] = 0;
    __syncthreads();
    for (int k = s0 + t; k < s1; k += 256)
        atomicAdd(&s_cnt[binned[k] >> 24], 1);
    __syncthreads();

    int v = s_cnt[t];
    s_scan[t] = v;
    __syncthreads();
#pragma unroll
    for (int o = 1; o < 256; o <<= 1) {
        int u = (t >= o) ? s_scan[t - o] : 0;
        __syncthreads();
        s_scan[t] += u;
        __syncthreads();
    }
    int excl = s_scan[t] - v;
    s_cur[t] = excl;
    float d = rsqrtf(1.0f + (float)v);
    dl[t] = d;
    if (t < nnode) {
        off[nbase + t] = s0 + excl;
        dis[nbase + t] = d;
    }
    if (b == NB - 1 && t == 0) off[N_NODES] = N_EDGES;
    __syncthreads();

    for (int k = s0 + t; k < s1; k += 256) {
        unsigned p = binned[k];
        int n = (int)(p >> 24);
        int r = atomicAdd(&s_cur[n], 1);
        sorted_src[s0 + r] = (int)(p & 0xFFFFFFu);
    }

    // in-place bf16 pre-scale of this bucket's hb rows (coalesced 16 KB)
    uint2* hv = reinterpret_cast<uint2*>(hb) + (size_t)nbase * 8;
    for (int tt = t; tt < nnode * 8; tt += 256) {
        uint2 w = hv[tt];
        float dd = dl[tt >> 3];
        w.x = bf16rne(bflo(w.x) * dd) | (bf16rne(bfhi(w.x) * dd) << 16);
        w.y = bf16rne(bflo(w.y) * dd) | (bf16rne(bfhi(w.y) * dd) << 16);
        hv[tt] = w;
    }
}

// ---------------------------------------------------------------------------
// K4: per-node aggregation + fused BN-stats.  4 threads/node, uint4 (16 B)
//     gathers — 4 lanes cover a 64 B row exactly; halves VMEM instruction
//     count vs 8-thread/uint2 at the same bytes/lines in flight.
//     4-wide edge ILP with idx double-buffer; 2 accumulator banks.
//     agg[n] = (hs[n] + sum_{in(n)} hs[s]) * dis[n]
// ---------------------------------------------------------------------------
__global__ void aggregate_kernel(const int* __restrict__ off,
                                 const int* __restrict__ sorted_src,
                                 const unsigned* __restrict__ hb,
                                 const float* __restrict__ dis,
                                 float* __restrict__ agg,
                                 float* __restrict__ stats) {
    int t = blockIdx.x * blockDim.x + threadIdx.x;
    int node = t >> 2;
    int c = t & 3;                 // 8-feature slice (16 B of the 64 B row)
    bool active = node < N_NODES;

    float o[8];
#pragma unroll
    for (int j = 0; j < 8; ++j) o[j] = 0.0f;

    if (active) {
        const uint4* hrow = reinterpret_cast<const uint4*>(hb);
        float dn = dis[node];
        uint4 hp = hrow[(size_t)node * 4 + c];
        float a0[8], a1[8];
        a0[0] = bflo(hp.x); a0[1] = bfhi(hp.x);
        a0[2] = bflo(hp.y); a0[3] = bfhi(hp.y);
        a0[4] = bflo(hp.z); a0[5] = bfhi(hp.z);
        a0[6] = bflo(hp.w); a0[7] = bfhi(hp.w);
#pragma unroll
        for (int j = 0; j < 8; ++j) a1[j] = 0.0f;

        int b0 = off[node], e0 = off[node + 1];
        int cnt4 = (e0 - b0) >> 2;
        int k = b0;
        int p0 = 0, p1 = 0, p2 = 0, p3 = 0;
        if (cnt4 > 0) {
            p0 = sorted_src[k];     p1 = sorted_src[k + 1];
            p2 = sorted_src[k + 2]; p3 = sorted_src[k + 3];
        }
        for (int it = 0; it < cnt4; ++it) {
            int kn = k + 4;
            int n0 = p0, n1 = p1, n2 = p2, n3 = p3;
            if (it + 1 < cnt4) {                    // prefetch next chunk idx
                n0 = sorted_src[kn];     n1 = sorted_src[kn + 1];
                n2 = sorted_src[kn + 2]; n3 = sorted_src[kn + 3];
            }
            uint4 v0 = hrow[(size_t)p0 * 4 + c];
            uint4 v1 = hrow[(size_t)p1 * 4 + c];
            uint4 v2 = hrow[(size_t)p2 * 4 + c];
            uint4 v3 = hrow[(size_t)p3 * 4 + c];
            a0[0] += bflo(v0.x); a0[1] += bfhi(v0.x);
            a0[2] += bflo(v0.y); a0[3] += bfhi(v0.y);
            a0[4] += bflo(v0.z); a0[5] += bfhi(v0.z);
            a0[6] += bflo(v0.w); a0[7] += bfhi(v0.w);
            a1[0] += bflo(v1.x); a1[1] += bfhi(v1.x);
            a1[2] += bflo(v1.y); a1[3] += bfhi(v1.y);
            a1[4] += bflo(v1.z); a1[5] += bfhi(v1.z);
            a1[6] += bflo(v1.w); a1[7] += bfhi(v1.w);
            a0[0] += bflo(v2.x); a0[1] += bfhi(v2.x);
            a0[2] += bflo(v2.y); a0[3] += bfhi(v2.y);
            a0[4] += bflo(v2.z); a0[5] += bfhi(v2.z);
            a0[6] += bflo(v2.w); a0[7] += bfhi(v2.w);
            a1[0] += bflo(v3.x); a1[1] += bfhi(v3.x);
            a1[2] += bflo(v3.y); a1[3] += bfhi(v3.y);
            a1[4] += bflo(v3.z); a1[5] += bfhi(v3.z);
            a1[6] += bflo(v3.w); a1[7] += bfhi(v3.w);
            p0 = n0; p1 = n1; p2 = n2; p3 = n3;
            k = kn;
        }
        for (; k < e0; ++k) {
            int s = sorted_src[k];
            uint4 v = hrow[(size_t)s * 4 + c];
            a0[0] += bflo(v.x); a0[1] += bfhi(v.x);
            a0[2] += bflo(v.y); a0[3] += bfhi(v.y);
            a0[4] += bflo(v.z); a0[5] += bfhi(v.z);
            a0[6] += bflo(v.w); a0[7] += bfhi(v.w);
        }
#pragma unroll
        for (int j = 0; j < 8; ++j) o[j] = (a0[j] + a1[j]) * dn;
        float4 w0 = {o[0], o[1], o[2], o[3]};
        float4 w1 = {o[4], o[5], o[6], o[7]};
        float4* ag = reinterpret_cast<float4*>(agg) + (size_t)node * 8 + c * 2;
        ag[0] = w0;
        ag[1] = w1;
    }

    // block-level stats reduce (all 256 threads reach barriers)
    __shared__ float S[256 * 9];   // pad 9: write/read bank-safe
    __shared__ float Q[256 * 9];
#pragma unroll
    for (int j = 0; j < 8; ++j) {
        S[threadIdx.x * 9 + j] = o[j];
        Q[threadIdx.x * 9 + j] = o[j] * o[j];
    }
    __syncthreads();
    if (threadIdx.x < 32) {
        int cc = threadIdx.x >> 3, j = threadIdx.x & 7;   // feature f = cc*8+j = tid
        float s = 0.0f, q = 0.0f;
#pragma unroll
        for (int w = 0; w < 64; ++w) {                    // threads with tid&3==cc
            int tid = (w << 2) | cc;
            s += S[tid * 9 + j];
            q += Q[tid * 9 + j];
        }
        float* rep = stats + 64 * (blockIdx.x & (NREP - 1));
        atomicAdd(&rep[threadIdx.x], s);
        atomicAdd(&rep[32 + threadIdx.x], q);
    }
}

// ---------------------------------------------------------------------------
// K5: out = relu(agg*A + B) @ W_cls + b_cls   (BN fold from NREP stat replicas)
// ---------------------------------------------------------------------------
__global__ void cls_kernel(const float* __restrict__ agg,
                           const float* __restrict__ stats,
                           const float* __restrict__ gamma,
                           const float* __restrict__ beta,
                           const float* __restrict__ W_cls,
                           const float* __restrict__ b_cls,
                           float* __restrict__ out) {
    __shared__ float sA[HID];
    __shared__ float sB[HID];
    __shared__ float sW[HID * N_CLS];
    __shared__ float sb[N_CLS];
    if (threadIdx.x < HID) {
        float sum = 0.0f, sq = 0.0f;
#pragma unroll
        for (int r = 0; r < NREP; ++r) {
            sum += stats[r * 64 + threadIdx.x];
            sq  += stats[r * 64 + 32 + threadIdx.x];
        }
        const float invN = 1.0f / (float)N_NODES;
        float mean = sum * invN;
        float var = sq * invN - mean * mean;
        float inv = rsqrtf(var + BN_EPS);
        float A = gamma[threadIdx.x] * inv;
        sA[threadIdx.x] = A;
        sB[threadIdx.x] = beta[threadIdx.x] - mean * A;
    }
    for (int t = threadIdx.x; t < HID * N_CLS; t += blockDim.x) sW[t] = W_cls[t];
    if (threadIdx.x < N_CLS) sb[threadIdx.x] = b_cls[threadIdx.x];
    __syncthreads();

    int i = blockIdx.x * blockDim.x + threadIdx.x;
    if (i >= N_NODES) return;

    float acc[N_CLS];
#pragma unroll
    for (int c = 0; c < N_CLS; ++c) acc[c] = sb[c];
#pragma unroll
    for (int f = 0; f < HID; ++f) {
        float t = fmaxf(fmaf(agg[(size_t)i * HID + f], sA[f], sB[f]), 0.0f);
#pragma unroll
        for (int c = 0; c < N_CLS; ++c) acc[c] = fmaf(t, sW[f * N_CLS + c], acc[c]);
    }
#pragma unroll
    for (int c = 0; c < N_CLS; ++c) out[(size_t)i * N_CLS + c] = acc[c];
}

// ---------------------------------------------------------------------------
extern "C" void kernel_launch(void* const* d_in, const int* in_sizes, int n_in,
                              void* d_out, int out_size, void* d_ws, size_t ws_size,
                              hipStream_t stream) {
    const float* x     = (const float*)d_in[0];
    const int*   edge  = (const int*)d_in[1];   // [2, E] int32
    const float* W_emb = (const float*)d_in[2];
    const float* b_emb = (const float*)d_in[3];
    const float* W_gcn = (const float*)d_in[4];
    // d_in[5] = b_gcn: cancels exactly in BatchNorm -> skip
    const float* gamma = (const float*)d_in[6];
    const float* beta  = (const float*)d_in[7];
    const float* W_cls = (const float*)d_in[8];
    const float* b_cls = (const float*)d_in[9];
    float* out = (float*)d_out;

    // workspace layout (~49 MB)
    unsigned*     hb         = (unsigned*)d_ws;                 // N*HID/2 uints (bf16 x2)
    float*        agg        = (float*)(hb + (size_t)N_NODES * HID / 2);  // N*HID
    float*        dis        = agg + (size_t)N_NODES * HID;     // N
    int*          off        = (int*)(dis + N_NODES);           // N+1
    int*          bcnt       = off + N_NODES + 1;               // NB
    int*          boff       = bcnt + NB;                       // NB+1
    int*          bcur       = boff + NB + 1;                   // NB
    unsigned int* binned     = (unsigned int*)(bcur + NB);      // E
    int*          sorted_src = (int*)(binned + N_EDGES);        // E
    float*        stats      = (float*)(sorted_src + N_EDGES);  // 64*NREP

    hipMemsetAsync(bcnt, 0, NB * sizeof(int), stream);

    const int* src = edge;
    const int* dst = edge + N_EDGES;

    embed_hist_kernel<<<NBLK_EMB + NBLK_H, 256, 0, stream>>>(x, W_emb, b_emb, W_gcn,
                                                             hb, dst, bcnt);
    bucket_scan_kernel<<<1, 1024, 0, stream>>>(bcnt, boff, bcur, stats);
    bin_edges_kernel<<<NBLK_BIN, 512, 0, stream>>>(src, dst, bcur, binned);
    bucket_csr_kernel<<<NB, 256, 0, stream>>>(boff, binned, sorted_src, off, dis, hb);
    aggregate_kernel<<<(N_NODES * 4 + 255) / 256, 256, 0, stream>>>(off, sorted_src,
                                                                    hb, dis, agg, stats);
    cls_kernel<<<(N_NODES + 255) / 256, 256, 0, stream>>>(agg, stats, gamma, beta,
                                                          W_cls, b_cls, out);
}